// Round 1
// baseline (268.557 us; speedup 1.0000x reference)
//
#include <hip/hip_runtime.h>

#define DEV_INLINE __device__ __forceinline__

// Problem dims (fixed by setup_inputs)
constexpr int B = 16, T = 4096, C = 512, K = 3;
constexpr int NC = 64;           // chunks along T
constexpr int L  = T / NC;       // 64 steps per chunk
constexpr int C4 = C / 4;        // 128 float4 lanes across channels
constexpr float EPS = 1e-4f;

// ws layout (in floats):
//   [TAB_A,   +K*C) : a[k][c]           (clamped sigmoid)
//   [TAB_AL,  +K*C) : a[k][c]^L
//   [TAB_MIX, +K*C) : softmax mix transposed to [k][c]
//   [CARRY_OFF, +B*NC*K*C) : pass1 local suffixes -> pass2 rewrites to chunk incoming states
constexpr size_t TAB_A     = 0;
constexpr size_t TAB_AL    = (size_t)K * C;
constexpr size_t TAB_MIX   = (size_t)2 * K * C;
constexpr size_t CARRY_OFF = (size_t)4 * K * C;   // 6144 floats = 24 KiB (16B aligned)

DEV_INLINE float4 f4mul(float4 a, float4 b) {
  return make_float4(a.x * b.x, a.y * b.y, a.z * b.z, a.w * b.w);
}
DEV_INLINE float4 f4fma(float4 a, float4 b, float4 c) {
  return make_float4(fmaf(a.x, b.x, c.x), fmaf(a.y, b.y, c.y),
                     fmaf(a.z, b.z, c.z), fmaf(a.w, b.w, c.w));
}
DEV_INLINE float4 f4onesub(float4 a) {
  return make_float4(1.f - a.x, 1.f - a.y, 1.f - a.z, 1.f - a.w);
}

// ---------------- prep: per-channel tables ----------------
__global__ void ema_prep(const float* __restrict__ logit_alpha,
                         const float* __restrict__ mix_logits,
                         float* __restrict__ ws) {
  int c = blockIdx.x * blockDim.x + threadIdx.x;
  if (c >= C) return;
  #pragma unroll
  for (int k = 0; k < K; ++k) {
    float la = logit_alpha[k * C + c];
    float a  = 1.0f / (1.0f + __expf(-la));
    a = fminf(fmaxf(a, EPS), 1.0f - EPS);
    ws[TAB_A + k * C + c] = a;
    float p = a;                 // a^L via repeated squaring, L = 64 = 2^6
    #pragma unroll
    for (int s = 0; s < 6; ++s) p = p * p;
    ws[TAB_AL + k * C + c] = p;
  }
  float m0 = mix_logits[c * K + 0];
  float m1 = mix_logits[c * K + 1];
  float m2 = mix_logits[c * K + 2];
  float mx = fmaxf(m0, fmaxf(m1, m2));
  float e0 = __expf(m0 - mx), e1 = __expf(m1 - mx), e2 = __expf(m2 - mx);
  float inv = 1.0f / (e0 + e1 + e2);
  ws[TAB_MIX + 0 * C + c] = e0 * inv;
  ws[TAB_MIX + 1 * C + c] = e1 * inv;
  ws[TAB_MIX + 2 * C + c] = e2 * inv;
}

// ---------------- pass1: per-chunk local suffix (zero-init EMA over the chunk) ----------------
__global__ __launch_bounds__(128) void ema_pass1(const float* __restrict__ x,
                                                 float* __restrict__ ws) {
  const int c4 = threadIdx.x;          // 0..C4-1
  const int bi = blockIdx.x;           // b*NC + chunk
  const int i  = bi & (NC - 1);

  const float4* aT = (const float4*)(ws + TAB_A);
  const float4 a0 = aT[0 * C4 + c4];
  const float4 a1 = aT[1 * C4 + c4];
  const float4 a2 = aT[2 * C4 + c4];
  const float4 b0 = f4onesub(a0), b1 = f4onesub(a1), b2 = f4onesub(a2);

  // x base for this (b, chunk): chunk covers t in [i*L, i*L+L)
  const float4* xb = (const float4*)x + (size_t)bi * L * C4 + c4;  // bi*L == (b*T + i*L)/... since T = NC*L

  float4 y0, y1, y2;
  int jstart;
  if (i == 0) {
    // chunk 0: y[0] = x[0] exactly (no incoming state)
    float4 x0 = xb[0];
    y0 = x0; y1 = x0; y2 = x0;
    jstart = 1;
  } else {
    y0 = make_float4(0.f, 0.f, 0.f, 0.f);
    y1 = y0; y2 = y0;
    jstart = 0;
  }

  #pragma unroll 4
  for (int j = jstart; j < L; ++j) {
    float4 xv = xb[(size_t)j * C4];
    y0 = f4fma(a0, y0, f4mul(b0, xv));
    y1 = f4fma(a1, y1, f4mul(b1, xv));
    y2 = f4fma(a2, y2, f4mul(b2, xv));
  }

  float4* carry = (float4*)(ws + CARRY_OFF);
  const size_t cb = ((size_t)bi * K) * C4 + c4;
  carry[cb + 0 * C4] = y0;
  carry[cb + 1 * C4] = y1;
  carry[cb + 2 * C4] = y2;
}

// ---------------- pass2: sequential scan over chunk carries ----------------
// Rewrites carry[b][i][k][c] (i>=1) with the exact incoming state for chunk i.
__global__ __launch_bounds__(256) void ema_pass2(float* __restrict__ ws) {
  int idx = blockIdx.x * blockDim.x + threadIdx.x;   // over B*K*C4
  if (idx >= B * K * C4) return;
  const int c4 = idx % C4;
  const int k  = (idx / C4) % K;
  const int b  = idx / (C4 * K);

  const float4 A = ((const float4*)(ws + TAB_AL))[k * C4 + c4];
  float4* carry = (float4*)(ws + CARRY_OFF);
  const size_t stride = (size_t)K * C4;              // per-chunk stride
  const size_t base = ((size_t)b * NC) * stride + (size_t)k * C4 + c4;

  float4 S = carry[base];                            // chunk0 end state (exact, x0-init)
  for (int i = 1; i < NC; ++i) {
    const size_t idxi = base + (size_t)i * stride;
    float4 t = carry[idxi];
    carry[idxi] = S;                                 // incoming state for chunk i
    S = f4fma(A, S, t);                              // end state of chunk i
  }
}

// ---------------- pass3: re-run recurrence from exact incoming state, fuse mix, write out ---------
__global__ __launch_bounds__(128) void ema_pass3(const float* __restrict__ x,
                                                 const float* __restrict__ ws,
                                                 float* __restrict__ out) {
  const int c4 = threadIdx.x;
  const int bi = blockIdx.x;
  const int i  = bi & (NC - 1);

  const float4* aT = (const float4*)(ws + TAB_A);
  const float4* mT = (const float4*)(ws + TAB_MIX);
  const float4 a0 = aT[0 * C4 + c4];
  const float4 a1 = aT[1 * C4 + c4];
  const float4 a2 = aT[2 * C4 + c4];
  const float4 b0 = f4onesub(a0), b1 = f4onesub(a1), b2 = f4onesub(a2);
  const float4 m0 = mT[0 * C4 + c4];
  const float4 m1 = mT[1 * C4 + c4];
  const float4 m2 = mT[2 * C4 + c4];

  const float4* xb = (const float4*)x   + (size_t)bi * L * C4 + c4;
  float4*       ob = (float4*)out       + (size_t)bi * L * C4 + c4;
  const float4* carry = (const float4*)(ws + CARRY_OFF);

  float4 y0, y1, y2;
  int jstart;
  if (i == 0) {
    float4 x0 = xb[0];
    y0 = x0; y1 = x0; y2 = x0;
    // t=0 output: sum_k mix_k * x0  (== x0 up to rounding)
    ob[0] = f4fma(m0, y0, f4fma(m1, y1, f4mul(m2, y2)));
    jstart = 1;
  } else {
    const size_t cb = ((size_t)bi * K) * C4 + c4;
    y0 = carry[cb + 0 * C4];
    y1 = carry[cb + 1 * C4];
    y2 = carry[cb + 2 * C4];
    jstart = 0;
  }

  #pragma unroll 4
  for (int j = jstart; j < L; ++j) {
    float4 xv = xb[(size_t)j * C4];
    y0 = f4fma(a0, y0, f4mul(b0, xv));
    y1 = f4fma(a1, y1, f4mul(b1, xv));
    y2 = f4fma(a2, y2, f4mul(b2, xv));
    ob[(size_t)j * C4] = f4fma(m0, y0, f4fma(m1, y1, f4mul(m2, y2)));
  }
}

extern "C" void kernel_launch(void* const* d_in, const int* in_sizes, int n_in,
                              void* d_out, int out_size, void* d_ws, size_t ws_size,
                              hipStream_t stream) {
  const float* x           = (const float*)d_in[0];
  const float* logit_alpha = (const float*)d_in[1];
  const float* mix_logits  = (const float*)d_in[2];
  float* out = (float*)d_out;
  float* ws  = (float*)d_ws;

  ema_prep<<<(C + 255) / 256, 256, 0, stream>>>(logit_alpha, mix_logits, ws);
  ema_pass1<<<B * NC, 128, 0, stream>>>(x, ws);
  ema_pass2<<<(B * K * C4 + 255) / 256, 256, 0, stream>>>(ws);
  ema_pass3<<<B * NC, 128, 0, stream>>>(x, ws, out);
}